// Round 1
// baseline (186.218 us; speedup 1.0000x reference)
//
#include <hip/hip_runtime.h>

#define E_EDGES 327680
#define D 128
#define BM 128      // edges per block
#define NW 4        // waves per block (each wave owns 32 edges)

typedef __bf16 bf16x8 __attribute__((ext_vector_type(8)));
typedef float  f32x4  __attribute__((ext_vector_type(4)));

// d_ws layout (bf16 weight fragments, B-operand order for mfma_f32_16x16x32_bf16):
//   per (kblock, ntile): 64 lanes x 16B, lane l holds W[k0+(l>>4)*8+j][ntile*16+(l&15)]
//   L1: 16 kblocks, L2/3/4: 4 kblocks each; 8 ntiles; layout [kblock][ntile][lane]
#define L1_OFF 0
#define L2_OFF 131072
#define L3_OFF 163840
#define L4_OFF 196608
#define WS_BYTES 229376

__device__ __forceinline__ unsigned short f2bf(float f) {
  unsigned int u = __builtin_bit_cast(unsigned int, f);
  u += 0x7fffu + ((u >> 16) & 1u);   // round-to-nearest-even
  return (unsigned short)(u >> 16);
}

__global__ __launch_bounds__(256) void prep_weights(
    const float* __restrict__ W1, const float* __restrict__ W2,
    const float* __restrict__ W3, const float* __restrict__ W4,
    unsigned short* __restrict__ ws)
{
  int tid = blockIdx.x * 256 + threadIdx.x;
  if (tid >= 224 * 64) return;
  int lane = tid & 63;
  int frag = tid >> 6;                 // 0..223 = [kblock*8 + ntile] per layer
  const float* W; int base_us; int lf;
  if (frag < 128)      { W = W1; base_us = L1_OFF / 2; lf = frag; }
  else if (frag < 160) { W = W2; base_us = L2_OFF / 2; lf = frag - 128; }
  else if (frag < 192) { W = W3; base_us = L3_OFF / 2; lf = frag - 160; }
  else                 { W = W4; base_us = L4_OFF / 2; lf = frag - 192; }
  int kb = lf >> 3, nt = lf & 7;
  int k0 = kb * 32 + (lane >> 4) * 8;
  int n  = nt * 16 + (lane & 15);
  unsigned int pk[4];
#pragma unroll
  for (int j = 0; j < 4; ++j) {
    unsigned int lo = f2bf(W[(size_t)(k0 + 2 * j    ) * D + n]);
    unsigned int hi = f2bf(W[(size_t)(k0 + 2 * j + 1) * D + n]);
    pk[j] = lo | (hi << 16);
  }
  *(uint4*)(ws + base_us + ((size_t)lf * 64 + lane) * 8) =
      make_uint4(pk[0], pk[1], pk[2], pk[3]);
}

__global__ __launch_bounds__(256) void edge_mlp(
    const float* __restrict__ recv, const float* __restrict__ send,
    const float* __restrict__ edge, const float* __restrict__ glob,
    const float* __restrict__ b1, const float* __restrict__ b2,
    const float* __restrict__ b3, const float* __restrict__ b4,
    const unsigned short* __restrict__ ws,
    float* __restrict__ out)
{
  // per-wave private 8KB LDS slice: 32 rows x 128 bf16, XOR-swizzled
  __shared__ __attribute__((aligned(16))) char smem[NW * 8192];
  const int lane = threadIdx.x & 63;
  const int wid  = threadIdx.x >> 6;
  char* wbuf = smem + wid * 8192;
  const int row0 = blockIdx.x * BM + wid * 32;   // this wave's first edge row
  const int arow = lane & 15;
  const int kgrp = lane >> 4;

  f32x4 acc[2][8];
#pragma unroll
  for (int m = 0; m < 2; ++m)
#pragma unroll
    for (int n = 0; n < 8; ++n) acc[m][n] = (f32x4)0.0f;

  // ---------------- layer 1: x = [recv | send | edge | g], K = 512 ----------------
#pragma unroll
  for (int c = 0; c < 4; ++c) {
    const float* src = (c == 0) ? recv : (c == 1) ? send : (c == 2) ? edge : glob;
    // stage this wave's 32x128 f32 chunk -> bf16 -> swizzled LDS
#pragma unroll
    for (int i = 0; i < 16; ++i) {
      int flat = i * 64 + lane;
      int r  = flat >> 5;          // 0..31
      int c4 = flat & 31;          // float4 index along the row
      float4 v;
      if (c == 3) v = ((const float4*)glob)[c4];                       // broadcast row
      else        v = ((const float4*)(src + (size_t)(row0 + r) * D))[c4];
      unsigned int lo = (unsigned int)f2bf(v.x) | ((unsigned int)f2bf(v.y) << 16);
      unsigned int hi = (unsigned int)f2bf(v.z) | ((unsigned int)f2bf(v.w) << 16);
      int colB = c4 * 8;
      int addr = r * 256 + (((colB & ~15) ^ ((r & 7) << 4)) | (colB & 8));
      *(uint2*)(wbuf + addr) = make_uint2(lo, hi);
    }
    // 4 K-steps of 32 over this chunk
#pragma unroll
    for (int kk = 0; kk < 4; ++kk) {
      int kblock = c * 4 + kk;
      const unsigned short* wp = ws + L1_OFF / 2 + ((size_t)(kblock * 8) * 64 + lane) * 8;
      bf16x8 bfr[8];
#pragma unroll
      for (int n = 0; n < 8; ++n) bfr[n] = *(const bf16x8*)(wp + (size_t)n * 512);
      bf16x8 afr[2];
#pragma unroll
      for (int m = 0; m < 2; ++m) {
        int rl = m * 16 + arow;
        int kB = kk * 64 + kgrp * 16;
        afr[m] = *(const bf16x8*)(wbuf + rl * 256 + (kB ^ ((rl & 7) << 4)));
      }
#pragma unroll
      for (int m = 0; m < 2; ++m)
#pragma unroll
        for (int n = 0; n < 8; ++n)
          acc[m][n] = __builtin_amdgcn_mfma_f32_16x16x32_bf16(afr[m], bfr[n], acc[m][n], 0, 0, 0);
    }
  }

  // epilogue: bias + relu + bf16 -> back into the wave's LDS slice (in place; same-wave DS is in-order)
  auto store_h = [&](const float* __restrict__ bias) {
#pragma unroll
    for (int n = 0; n < 8; ++n) {
      float bn = bias[n * 16 + arow];
#pragma unroll
      for (int m = 0; m < 2; ++m) {
#pragma unroll
        for (int r = 0; r < 4; ++r) {
          float v = fmaxf(acc[m][n][r] + bn, 0.0f);
          int rw   = m * 16 + kgrp * 4 + r;
          int colB = (n * 16 + arow) * 2;
          int addr = rw * 256 + (((colB & ~15) ^ ((rw & 7) << 4)) | (colB & 15));
          *(unsigned short*)(wbuf + addr) = f2bf(v);
        }
        acc[m][n] = (f32x4)0.0f;
      }
    }
  };

  auto do_layer = [&](int ws_us_off) {
#pragma unroll
    for (int kk = 0; kk < 4; ++kk) {
      const unsigned short* wp = ws + ws_us_off + ((size_t)(kk * 8) * 64 + lane) * 8;
      bf16x8 bfr[8];
#pragma unroll
      for (int n = 0; n < 8; ++n) bfr[n] = *(const bf16x8*)(wp + (size_t)n * 512);
      bf16x8 afr[2];
#pragma unroll
      for (int m = 0; m < 2; ++m) {
        int rl = m * 16 + arow;
        int kB = kk * 64 + kgrp * 16;
        afr[m] = *(const bf16x8*)(wbuf + rl * 256 + (kB ^ ((rl & 7) << 4)));
      }
#pragma unroll
      for (int m = 0; m < 2; ++m)
#pragma unroll
        for (int n = 0; n < 8; ++n)
          acc[m][n] = __builtin_amdgcn_mfma_f32_16x16x32_bf16(afr[m], bfr[n], acc[m][n], 0, 0, 0);
    }
  };

  store_h(b1);
  do_layer(L2_OFF / 2);
  store_h(b2);
  do_layer(L3_OFF / 2);
  store_h(b3);
  do_layer(L4_OFF / 2);

  // final layer: bias, no relu, f32 store
#pragma unroll
  for (int n = 0; n < 8; ++n) {
    float bn = b4[n * 16 + arow];
#pragma unroll
    for (int m = 0; m < 2; ++m)
#pragma unroll
      for (int r = 0; r < 4; ++r) {
        int rw = m * 16 + kgrp * 4 + r;
        out[(size_t)(row0 + rw) * D + n * 16 + arow] = acc[m][n][r] + bn;
      }
  }
}

extern "C" void kernel_launch(void* const* d_in, const int* in_sizes, int n_in,
                              void* d_out, int out_size, void* d_ws, size_t ws_size,
                              hipStream_t stream)
{
  const float* recv = (const float*)d_in[0];
  const float* send = (const float*)d_in[1];
  const float* edge = (const float*)d_in[2];
  const float* glob = (const float*)d_in[3];
  const float* W1 = (const float*)d_in[4];
  const float* b1 = (const float*)d_in[5];
  const float* W2 = (const float*)d_in[6];
  const float* b2 = (const float*)d_in[7];
  const float* W3 = (const float*)d_in[8];
  const float* b3 = (const float*)d_in[9];
  const float* W4 = (const float*)d_in[10];
  const float* b4 = (const float*)d_in[11];
  unsigned short* ws = (unsigned short*)d_ws;

  prep_weights<<<56, 256, 0, stream>>>(W1, W2, W3, W4, ws);
  edge_mlp<<<E_EDGES / BM, 256, 0, stream>>>(recv, send, edge, glob,
                                             b1, b2, b3, b4, ws, (float*)d_out);
}